// Round 3
// baseline (391.673 us; speedup 1.0000x reference)
//
#include <hip/hip_runtime.h>

// Problem: VOCAB=10000, EMB=100, T=80, UNITS=256, BATCH=4096 — ALL FP32 I/O.
// out = sigmoid(h2_T);  h_l,t = tanh(x_l,t @ Wl + h_l,t-1 @ Ul + bl)
//
// v10 theory (from v9 counters): v9's 192-reg pin + per-lane scalar P1 gather
// overflowed the 256-reg budget (WRITE 4->10.2MB spills, FETCH 12->35MB) and
// regressed. Structural fix: trade occupancy for register capacity:
//  - 256 thr = 4 waves, waves_per_eu(1,1) => full 512-reg unified file/wave.
//  - wave owns FOUR n-tiles (64 cols): U1+W2+U2 all reg-resident =
//    3*4*32 = 384 pinned frags (AGPR+VGPR unified) + 32 acc + ~50 transient
//    ~= 470 < 512. Zero weight re-loads, zero U2-LDS stream.
//  - A-frag re-read factor halves (4 waves instead of 8 read each state frag):
//    LDS/CU/step = 3 matmuls * 8 frags * 4 waves * 1KB = 96 KB (v8: 320 KB).
//  - P1 (= b1 + emb@W1, precomputed 10000x256 f16 table) staged per-step into
//    a small double-buffered LDS tile with COALESCED 16B loads (v9 did
//    scalar 2B global gathers), consumed as layer-1 acc initializers.
// MFMA/wave/step = 96 (~466 cy at 1 wave/SIMD, 8 indep chains); LDS floor
// ~1000 cy; est ~1500 cy/step vs v8's 7230.
#define BATCH 4096
#define TLEN  80
#define EMBD  100
#define UNITS 256

typedef _Float16 f16;
typedef __attribute__((ext_vector_type(8))) _Float16 h8;   // 8 f16 = 4 VGPR MFMA A/B frag
typedef __attribute__((ext_vector_type(4))) float f32x4;   // MFMA C/D frag

__device__ __forceinline__ float fast_tanh(float x) {
  x = fminf(fmaxf(x, -15.f), 15.f);
  float e = __expf(-2.f * x);
  return (1.f - e) / (1.f + e);
}
__device__ __forceinline__ float fast_sigmoid(float x) {
  x = fminf(fmaxf(x, -30.f), 30.f);
  return 1.f / (1.f + __expf(-x));
}

// ---------------- workspace layout (5.58 MB <= 6.04 MB proven available) ---
// P1 table: 10000 x 256 f16 = 5,120,000 B.  wf frags: 458,752 B.
// B-frag layout (16x16x32, r7-verified): lane holds B[k=quad*8+j][n=lane&15].
// ktg slots: W1 = 0..3 (unused by main kernel), U1 = 4..11, W2 = 12..19,
// U2 = 20..27.  (kept identical to v8/v9 for layout safety)
#define KT_ALL 28
#define OFF_P1 ((size_t)0)
#define P1_BYTES ((size_t)10000 * UNITS * 2)                // 5,120,000
#define OFF_WF  P1_BYTES
#define WF_BYTES ((size_t)KT_ALL * 16 * 64 * 8 * 2)         //   458,752
#define WS_NEED (OFF_WF + WF_BYTES)                          // 5,578,752 B

__device__ __forceinline__ size_t fidx(int ktg, int nt, int lane) {
  return (((size_t)ktg * 16 + nt) * 64 + lane) * 8;
}

// ---------------- precompute: weights -> swizzled fp16 B-frags (r10-verified)
__global__ __launch_bounds__(256) void k_split_w16(
    const float* __restrict__ W1, const float* __restrict__ U1,
    const float* __restrict__ W2, const float* __restrict__ U2,
    f16* __restrict__ wf)
{
  int gid = blockIdx.x * 256 + threadIdx.x;           // one per (ktg,nt,lane)
  if (gid >= KT_ALL * 16 * 64) return;
  int lane = gid & 63, nt = (gid >> 6) & 15, ktg = gid >> 10;
  const float* M; int Kact, ktl;
  if (ktg < 4)       { M = W1; Kact = EMBD;  ktl = ktg;      }
  else if (ktg < 12) { M = U1; Kact = UNITS; ktl = ktg - 4;  }
  else if (ktg < 20) { M = W2; Kact = UNITS; ktl = ktg - 12; }
  else               { M = U2; Kact = UNITS; ktl = ktg - 20; }
  int n = nt * 16 + (lane & 15);
  int kb = ktl * 32 + (lane >> 4) * 8;
  size_t base = fidx(ktg, nt, lane);
#pragma unroll
  for (int j = 0; j < 8; ++j) {
    int k = kb + j;
    wf[base + j] = (f16)((k < Kact) ? M[(size_t)k * UNITS + n] : 0.f);  // RNE
  }
}

// ---------------- precompute: P1[v][n] = b1[n] + emb[v,:] @ W1 (f32 math) --
__global__ __launch_bounds__(256) void k_p1(
    const float* __restrict__ emb, const float* __restrict__ W1,
    const float* __restrict__ b1, f16* __restrict__ p1t)
{
  __shared__ float er[16][EMBD];
  const int v0 = blockIdx.x * 16;
  for (int i = threadIdx.x; i < 16 * EMBD; i += 256) {
    int vv = i / EMBD, kk = i - vv * EMBD;
    er[vv][kk] = emb[(size_t)(v0 + vv) * EMBD + kk];
  }
  __syncthreads();
  const int n = threadIdx.x;
  float acc[16];
  const float bb = b1[n];
#pragma unroll
  for (int vv = 0; vv < 16; ++vv) acc[vv] = bb;
  for (int k = 0; k < EMBD; ++k) {
    float w = W1[(size_t)k * UNITS + n];
#pragma unroll
    for (int vv = 0; vv < 16; ++vv) acc[vv] += er[vv][k] * w;
  }
#pragma unroll
  for (int vv = 0; vv < 16; ++vv)
    p1t[(size_t)(v0 + vv) * UNITS + n] = (f16)acc[vv];
}

#define MFMA16(A, B, C) __builtin_amdgcn_mfma_f32_16x16x32_f16(A, B, C, 0, 0, 0)

// store tanh result into next-step A-frag (single f16; layout r7-verified):
// elem (row=m, col=k): kt=col>>5, lane'=((col>>3)&3)*16+row, j'=col&7
__device__ __forceinline__ void store_frag1(f16* __restrict__ f, int col, int row, float v) {
  int a = (col >> 5) * 512 + (((col >> 3) & 3) * 16 + row) * 8 + (col & 7);
  f[a] = (f16)v;
}

#define P1S 264   // p1s row stride in f16: 528B = 33*16 (b128-aligned),
                  // 132 dwords -> q-groups offset 16 banks: ~4-way max

// ---------------------------------------------------------------------------
// Main kernel v10: 256 threads = 4 waves, wave w owns n-tiles 4w..4w+3.
// ---------------------------------------------------------------------------
__global__ __launch_bounds__(256, 1)
__attribute__((amdgpu_waves_per_eu(1, 1)))
void rnn_ws6(
    const int* __restrict__ idx, const f16* __restrict__ p1t,
    const f16* __restrict__ wf, const float* __restrict__ b2,
    float* __restrict__ out)
{
  __shared__ __align__(16) f16 f1[2][4096];      // [buf][kt*512 + lane*8 + j]
  __shared__ __align__(16) f16 f2[2][4096];
  __shared__ __align__(16) f16 p1s[2][16 * P1S]; // [buf][row*P1S + col]

  const int tid  = threadIdx.x;
  const int lane = tid & 63;
  const int w    = tid >> 6;          // wave 0..3 -> n-tiles 4w..4w+3
  const int m    = lane & 15;
  const int q    = lane >> 4;
  const int b0   = blockIdx.x * 16;

  int cc[4];
  float b2v[4];
#pragma unroll
  for (int j = 0; j < 4; ++j) {
    cc[j] = (4 * w + j) * 16 + m;
    b2v[j] = b2[cc[j]];
  }

  // -------- persistent weight fragments: U1, W2, U2 x 4 n-tiles ------------
  h8 Bu1[4][8], Bw2[4][8], Bu2[4][8];
#pragma unroll
  for (int j = 0; j < 4; ++j)
#pragma unroll
    for (int kt = 0; kt < 8; ++kt) {
      Bu1[j][kt] = *(const h8*)(wf + fidx(4 + kt, 4 * w + j, lane));
      Bw2[j][kt] = *(const h8*)(wf + fidx(12 + kt, 4 * w + j, lane));
      Bu2[j][kt] = *(const h8*)(wf + fidx(20 + kt, 4 * w + j, lane));
    }
  // pin: origin becomes the asm -> no remat; unified VGPR+AGPR file holds 384
#pragma unroll
  for (int j = 0; j < 4; ++j)
#pragma unroll
    for (int kt = 0; kt < 8; ++kt) {
      asm volatile("" : "+v"(Bu1[j][kt]));
      asm volatile("" : "+v"(Bw2[j][kt]));
      asm volatile("" : "+v"(Bu2[j][kt]));
    }

  // -------- t=0 P1 stage (coalesced 16B loads) + zero states ---------------
  {
    int row = tid >> 4, part = tid & 15;                 // 16 thr x 32B / row
    int tk = idx[(size_t)(b0 + row) * TLEN + 0];
    const f16* src = p1t + (size_t)tk * UNITS + part * 16;
    *(h8*)&p1s[0][row * P1S + part * 16]     = *(const h8*)(src);
    *(h8*)&p1s[0][row * P1S + part * 16 + 8] = *(const h8*)(src + 8);
  }
  for (int i = tid; i < 4096; i += 256) {
    f1[0][i] = (f16)0.f;
    f2[0][i] = (f16)0.f;
  }
  __syncthreads();

  for (int t = 0; t < TLEN; ++t) {
    const int p = t & 1, qb = p ^ 1;

    // ---- acc init: x = P1[tok] (has b1 folded in), y = b2 -----------------
    f32x4 x[4], y[4];
#pragma unroll
    for (int j = 0; j < 4; ++j) {
#pragma unroll
      for (int r = 0; r < 4; ++r)
        x[j][r] = (float)p1s[p][(q * 4 + r) * P1S + cc[j]];
      y[j] = (f32x4){b2v[j], b2v[j], b2v[j], b2v[j]};
    }

    // ---- layer 1 (U1 on f1[p]) + layer 2a (U2 on f2[p]): 8 indep chains ---
#pragma unroll
    for (int kt = 0; kt < 8; ++kt) {
      h8 a1 = *(const h8*)&f1[p][kt * 512 + lane * 8];
      h8 a2 = *(const h8*)&f2[p][kt * 512 + lane * 8];
#pragma unroll
      for (int j = 0; j < 4; ++j) {
        x[j] = MFMA16(a1, Bu1[j][kt], x[j]);
        y[j] = MFMA16(a2, Bu2[j][kt], y[j]);
      }
    }

    // ---- stage next step's P1 (global latency hides under epi1+barrier) ---
    if (t + 1 < TLEN) {
      int row = tid >> 4, part = tid & 15;
      int tk = idx[(size_t)(b0 + row) * TLEN + (t + 1)];
      const f16* src = p1t + (size_t)tk * UNITS + part * 16;
      *(h8*)&p1s[qb][row * P1S + part * 16]     = *(const h8*)(src);
      *(h8*)&p1s[qb][row * P1S + part * 16 + 8] = *(const h8*)(src + 8);
    }

    // ---- layer-1 epilogue: tanh -> next A-frag ----------------------------
#pragma unroll
    for (int j = 0; j < 4; ++j)
#pragma unroll
      for (int r = 0; r < 4; ++r)
        store_frag1(f1[qb], cc[j], q * 4 + r, fast_tanh(x[j][r]));
    __syncthreads();                           // barrier 1: f1[qb] visible

    // ---- layer 2b: h1_new @ W2 --------------------------------------------
#pragma unroll
    for (int kt = 0; kt < 8; ++kt) {
      h8 ah = *(const h8*)&f1[qb][kt * 512 + lane * 8];
#pragma unroll
      for (int j = 0; j < 4; ++j)
        y[j] = MFMA16(ah, Bw2[j][kt], y[j]);
    }
#pragma unroll
    for (int j = 0; j < 4; ++j)
#pragma unroll
      for (int r = 0; r < 4; ++r) {
        int row = q * 4 + r;
        float tv = fast_tanh(y[j][r]);
        store_frag1(f2[qb], cc[j], row, tv);
        if (t == TLEN - 1)
          out[(size_t)(b0 + row) * UNITS + cc[j]] = fast_sigmoid(tv);
      }
    __syncthreads();                           // barrier 2: f2[qb] visible
  }
}

// ---------------------------------------------------------------------------
extern "C" void kernel_launch(void* const* d_in, const int* in_sizes, int n_in,
                              void* d_out, int out_size, void* d_ws, size_t ws_size,
                              hipStream_t stream)
{
  const int*   idx = (const int*)d_in[0];
  const float* emb = (const float*)d_in[1];
  const float* W1  = (const float*)d_in[2];
  const float* U1  = (const float*)d_in[3];
  const float* b1  = (const float*)d_in[4];
  const float* W2  = (const float*)d_in[5];
  const float* U2  = (const float*)d_in[6];
  const float* b2  = (const float*)d_in[7];
  // d_in[8] (Wd), d_in[9] (bd) dead in the reference output.
  float* out = (float*)d_out;

  f16* p1t = (f16*)((char*)d_ws + OFF_P1);
  f16* wf  = (f16*)((char*)d_ws + OFF_WF);
  k_p1<<<10000 / 16, 256, 0, stream>>>(emb, W1, b1, p1t);
  k_split_w16<<<(KT_ALL * 16 * 64 + 255) / 256, 256, 0, stream>>>(W1, U1, W2, U2, wf);
  rnn_ws6<<<BATCH / 16, 256, 0, stream>>>(idx, p1t, wf, b2, out);
}

// Round 4
// 336.731 us; speedup vs baseline: 1.1632x; 1.1632x over previous
//
#include <hip/hip_runtime.h>

// Problem: VOCAB=10000, EMB=100, T=80, UNITS=256, BATCH=4096 — ALL FP32 I/O.
// out = sigmoid(h2_T);  h_l,t = tanh(x_l,t @ Wl + h_l,t-1 @ Ul + bl)
//
// v11 theory (from v10 counters): v10's all-reg 4-wave config was latency-
// exposed (1 wave/SIMD, MfmaUtil 16.8) despite 3.3x less LDS traffic; v8's
// 2 waves/SIMD won. Keep 8 waves AND cut LDS via cross-t software pipeline:
// iteration i computes h1[i] AND h2[i-1]. Consequences:
//  - U1-chain (h1[i-1]@U1) and W2-chain (h1[i-1]@W2) read the SAME A-frags
//    -> load once, feed both. A-reads 24 -> 16 b128/wave/iter.
//  - everything read at iter i+1 is written at iter i -> ONE barrier/iter
//    (81 vs 160).
//  - U2 reg-resident via "+a" pins (AGPR class; VGPR class stays free for
//    transients — v9's "+v" squeeze at 2-wave budget is avoided). U2's
//    128 KB/step LDS stream gone. 192 pinned + 24 acc + ~35 transient ~ 250.
// Per-CU-iter LDS: 320 KB (v8) -> ~136 KB. P1 (= b1 + emb@W1 table) staged
// per-step with coalesced b128 loads into small double-buffered LDS tile.
#define BATCH 4096
#define TLEN  80
#define EMBD  100
#define UNITS 256

typedef _Float16 f16;
typedef __attribute__((ext_vector_type(8))) _Float16 h8;   // 8 f16 = 4 VGPR MFMA A/B frag
typedef __attribute__((ext_vector_type(4))) float f32x4;   // MFMA C/D frag

__device__ __forceinline__ float fast_tanh(float x) {
  x = fminf(fmaxf(x, -15.f), 15.f);
  float e = __expf(-2.f * x);
  return (1.f - e) / (1.f + e);
}
__device__ __forceinline__ float fast_sigmoid(float x) {
  x = fminf(fmaxf(x, -30.f), 30.f);
  return 1.f / (1.f + __expf(-x));
}

// ---------------- workspace layout (5.58 MB <= 6.04 MB proven available) ---
// P1 table: 10000 x 256 f16 = 5,120,000 B.  wf frags: 458,752 B.
// B-frag layout (16x16x32, r7-verified): lane holds B[k=quad*8+j][n=lane&15].
// ktg slots: W1 = 0..3 (unused by main kernel), U1 = 4..11, W2 = 12..19,
// U2 = 20..27.  (kept identical to v8/v9/v10 for layout safety)
#define KT_ALL 28
#define OFF_P1 ((size_t)0)
#define P1_BYTES ((size_t)10000 * UNITS * 2)                // 5,120,000
#define OFF_WF  P1_BYTES
#define WF_BYTES ((size_t)KT_ALL * 16 * 64 * 8 * 2)         //   458,752
#define WS_NEED (OFF_WF + WF_BYTES)                          // 5,578,752 B

__device__ __forceinline__ size_t fidx(int ktg, int nt, int lane) {
  return (((size_t)ktg * 16 + nt) * 64 + lane) * 8;
}

// ---------------- precompute: weights -> swizzled fp16 B-frags (r10-verified)
__global__ __launch_bounds__(256) void k_split_w16(
    const float* __restrict__ W1, const float* __restrict__ U1,
    const float* __restrict__ W2, const float* __restrict__ U2,
    f16* __restrict__ wf)
{
  int gid = blockIdx.x * 256 + threadIdx.x;           // one per (ktg,nt,lane)
  if (gid >= KT_ALL * 16 * 64) return;
  int lane = gid & 63, nt = (gid >> 6) & 15, ktg = gid >> 10;
  const float* M; int Kact, ktl;
  if (ktg < 4)       { M = W1; Kact = EMBD;  ktl = ktg;      }
  else if (ktg < 12) { M = U1; Kact = UNITS; ktl = ktg - 4;  }
  else if (ktg < 20) { M = W2; Kact = UNITS; ktl = ktg - 12; }
  else               { M = U2; Kact = UNITS; ktl = ktg - 20; }
  int n = nt * 16 + (lane & 15);
  int kb = ktl * 32 + (lane >> 4) * 8;
  size_t base = fidx(ktg, nt, lane);
#pragma unroll
  for (int j = 0; j < 8; ++j) {
    int k = kb + j;
    wf[base + j] = (f16)((k < Kact) ? M[(size_t)k * UNITS + n] : 0.f);  // RNE
  }
}

// ---------------- precompute: P1[v][n] = b1[n] + emb[v,:] @ W1 (f32 math) --
__global__ __launch_bounds__(256) void k_p1(
    const float* __restrict__ emb, const float* __restrict__ W1,
    const float* __restrict__ b1, f16* __restrict__ p1t)
{
  __shared__ float er[16][EMBD];
  const int v0 = blockIdx.x * 16;
  for (int i = threadIdx.x; i < 16 * EMBD; i += 256) {
    int vv = i / EMBD, kk = i - vv * EMBD;
    er[vv][kk] = emb[(size_t)(v0 + vv) * EMBD + kk];
  }
  __syncthreads();
  const int n = threadIdx.x;
  float acc[16];
  const float bb = b1[n];
#pragma unroll
  for (int vv = 0; vv < 16; ++vv) acc[vv] = bb;
  for (int k = 0; k < EMBD; ++k) {
    float w = W1[(size_t)k * UNITS + n];
#pragma unroll
    for (int vv = 0; vv < 16; ++vv) acc[vv] += er[vv][k] * w;
  }
#pragma unroll
  for (int vv = 0; vv < 16; ++vv)
    p1t[(size_t)(v0 + vv) * UNITS + n] = (f16)acc[vv];
}

#define MFMA16(A, B, C) __builtin_amdgcn_mfma_f32_16x16x32_f16(A, B, C, 0, 0, 0)

// store tanh result into next-step A-frag (single f16; layout r7-verified):
// elem (row=m, col=k): kt=col>>5, lane'=((col>>3)&3)*16+row, j'=col&7
__device__ __forceinline__ void store_frag1(f16* __restrict__ f, int col, int row, float v) {
  int a = (col >> 5) * 512 + (((col >> 3) & 3) * 16 + row) * 8 + (col & 7);
  f[a] = (f16)v;
}

#define P1S 264   // p1s row stride in f16: 528B; row offset 4 banks -> ~2-way

// ---------------------------------------------------------------------------
// Main kernel v11: 512 thr = 8 waves (2/SIMD), wave w owns n-tiles 2w, 2w+1.
// Iter i: h1[i] = tanh(P1[i] + h1[i-1]@U1);  h2[i-1] = tanh(b2 + h1[i-1]@W2
// + h2[i-2]@U2).  One barrier per iter.  U1/W2/U2 all AGPR-resident.
// ---------------------------------------------------------------------------
__global__ __launch_bounds__(512, 2)
__attribute__((amdgpu_waves_per_eu(2, 2)))
void rnn_ws7(
    const int* __restrict__ idx, const f16* __restrict__ p1t,
    const f16* __restrict__ wf, const float* __restrict__ b2,
    float* __restrict__ out)
{
  __shared__ __align__(16) f16 f1[2][4096];      // [buf][kt*512 + lane*8 + j]
  __shared__ __align__(16) f16 f2[2][4096];
  __shared__ __align__(16) f16 p1s[2][16 * P1S]; // [buf][row*P1S + col]

  const int tid  = threadIdx.x;
  const int lane = tid & 63;
  const int w    = tid >> 6;          // wave 0..7 -> n-tiles 2w, 2w+1
  const int m    = lane & 15;
  const int q    = lane >> 4;
  const int b0   = blockIdx.x * 16;
  const int c0   = (2 * w) * 16 + m;
  const int c1   = (2 * w + 1) * 16 + m;

  const float b2a = b2[c0], b2b = b2[c1];

  // P1 staging assignment: 32 threads/row, 8 f16 (16B) each
  const int srow = tid >> 5, spart = tid & 31;
  const int* tokp = idx + (size_t)(b0 + srow) * TLEN;

  // -------- persistent weight fragments: U1, W2, U2 (2 n-tiles each) -------
  h8 Bu1a[8], Bu1b[8], Bw2a[8], Bw2b[8], Bu2a[8], Bu2b[8];
#pragma unroll
  for (int kt = 0; kt < 8; ++kt) {
    Bu1a[kt] = *(const h8*)(wf + fidx(4 + kt, 2 * w, lane));
    Bu1b[kt] = *(const h8*)(wf + fidx(4 + kt, 2 * w + 1, lane));
    Bw2a[kt] = *(const h8*)(wf + fidx(12 + kt, 2 * w, lane));
    Bw2b[kt] = *(const h8*)(wf + fidx(12 + kt, 2 * w + 1, lane));
    Bu2a[kt] = *(const h8*)(wf + fidx(20 + kt, 2 * w, lane));
    Bu2b[kt] = *(const h8*)(wf + fidx(20 + kt, 2 * w + 1, lane));
  }
  // pin into the AGPR class: weight frags live in AGPRs (MFMA reads A/B from
  // AGPR natively on gfx950); VGPR class keeps the loop transients.
#pragma unroll
  for (int kt = 0; kt < 8; ++kt) {
    asm volatile("" : "+a"(Bu1a[kt])); asm volatile("" : "+a"(Bu1b[kt]));
    asm volatile("" : "+a"(Bw2a[kt])); asm volatile("" : "+a"(Bw2b[kt]));
    asm volatile("" : "+a"(Bu2a[kt])); asm volatile("" : "+a"(Bu2b[kt]));
  }

  // -------- init: zero state buffers; stage P1[0] into p1s[0] --------------
  for (int i = tid; i < 8192; i += 512) {
    ((f16*)f1)[i] = (f16)0.f;
    ((f16*)f2)[i] = (f16)0.f;
  }
  {
    int tk = tokp[0];
    *(h8*)&p1s[0][srow * P1S + spart * 8] =
        *(const h8*)(p1t + (size_t)tk * UNITS + spart * 8);
  }
  __syncthreads();

  // -------- iter 0 (peeled): h1[0] = tanh(P1[0]) ---------------------------
  {
#pragma unroll
    for (int r = 0; r < 4; ++r) {
      int row = q * 4 + r;
      store_frag1(f1[0], c0, row, fast_tanh((float)p1s[0][row * P1S + c0]));
      store_frag1(f1[0], c1, row, fast_tanh((float)p1s[0][row * P1S + c1]));
    }
    int tk = tokp[1];
    *(h8*)&p1s[1][srow * P1S + spart * 8] =
        *(const h8*)(p1t + (size_t)tk * UNITS + spart * 8);
  }
  __syncthreads();

  // -------- main loop: i = 1..79 — compute h1[i] and h2[i-1] ---------------
  for (int i = 1; i < TLEN; ++i) {
    const int wr = i & 1, rd = wr ^ 1;

    // stage P1[i+1] early (HBM/L2 latency hides under the MFMA chains);
    // p1s[rd] was last read at iter i-1 (pre-barrier) -> safe to overwrite.
    if (i + 1 < TLEN) {
      int tk = tokp[i + 1];
      *(h8*)&p1s[rd][srow * P1S + spart * 8] =
          *(const h8*)(p1t + (size_t)tk * UNITS + spart * 8);
    }

    // acc init: x = P1[i] (b1 folded in), yA = b2, yB = 0
    f32x4 x0, x1;
#pragma unroll
    for (int r = 0; r < 4; ++r) {
      int row = q * 4 + r;
      x0[r] = (float)p1s[wr][row * P1S + c0];
      x1[r] = (float)p1s[wr][row * P1S + c1];
    }
    f32x4 yA0 = (f32x4){b2a, b2a, b2a, b2a};
    f32x4 yA1 = (f32x4){b2b, b2b, b2b, b2b};
    f32x4 yB0 = (f32x4){0.f, 0.f, 0.f, 0.f};
    f32x4 yB1 = (f32x4){0.f, 0.f, 0.f, 0.f};

    // 6 chains x 8 MFMA; a1 (= h1[i-1] frag) shared by U1 and W2 chains
#pragma unroll
    for (int kt = 0; kt < 8; ++kt) {
      h8 a1 = *(const h8*)&f1[rd][kt * 512 + lane * 8];
      h8 a2 = *(const h8*)&f2[rd][kt * 512 + lane * 8];
      x0  = MFMA16(a1, Bu1a[kt], x0);
      x1  = MFMA16(a1, Bu1b[kt], x1);
      yA0 = MFMA16(a1, Bw2a[kt], yA0);
      yA1 = MFMA16(a1, Bw2b[kt], yA1);
      yB0 = MFMA16(a2, Bu2a[kt], yB0);
      yB1 = MFMA16(a2, Bu2b[kt], yB1);
    }

    // epilogues: h1[i] -> f1[wr];  h2[i-1] -> f2[wr]
#pragma unroll
    for (int r = 0; r < 4; ++r) {
      int row = q * 4 + r;
      store_frag1(f1[wr], c0, row, fast_tanh(x0[r]));
      store_frag1(f1[wr], c1, row, fast_tanh(x1[r]));
      store_frag1(f2[wr], c0, row, fast_tanh(yA0[r] + yB0[r]));
      store_frag1(f2[wr], c1, row, fast_tanh(yA1[r] + yB1[r]));
    }
    __syncthreads();                 // the ONLY barrier per iteration
  }

  // -------- tail: h2[79] = tanh(b2 + h1[79]@W2 + h2[78]@U2) -> out ---------
  {
    const int rd = (TLEN - 1) & 1;   // = 1: h1[79] in f1[1], h2[78] in f2[1]
    f32x4 yA0 = (f32x4){b2a, b2a, b2a, b2a};
    f32x4 yA1 = (f32x4){b2b, b2b, b2b, b2b};
    f32x4 yB0 = (f32x4){0.f, 0.f, 0.f, 0.f};
    f32x4 yB1 = (f32x4){0.f, 0.f, 0.f, 0.f};
#pragma unroll
    for (int kt = 0; kt < 8; ++kt) {
      h8 a1 = *(const h8*)&f1[rd][kt * 512 + lane * 8];
      h8 a2 = *(const h8*)&f2[rd][kt * 512 + lane * 8];
      yA0 = MFMA16(a1, Bw2a[kt], yA0);
      yA1 = MFMA16(a1, Bw2b[kt], yA1);
      yB0 = MFMA16(a2, Bu2a[kt], yB0);
      yB1 = MFMA16(a2, Bu2b[kt], yB1);
    }
#pragma unroll
    for (int r = 0; r < 4; ++r) {
      int row = q * 4 + r;
      out[(size_t)(b0 + row) * UNITS + c0] = fast_sigmoid(fast_tanh(yA0[r] + yB0[r]));
      out[(size_t)(b0 + row) * UNITS + c1] = fast_sigmoid(fast_tanh(yA1[r] + yB1[r]));
    }
  }
}

// ---------------------------------------------------------------------------
extern "C" void kernel_launch(void* const* d_in, const int* in_sizes, int n_in,
                              void* d_out, int out_size, void* d_ws, size_t ws_size,
                              hipStream_t stream)
{
  const int*   idx = (const int*)d_in[0];
  const float* emb = (const float*)d_in[1];
  const float* W1  = (const float*)d_in[2];
  const float* U1  = (const float*)d_in[3];
  const float* b1  = (const float*)d_in[4];
  const float* W2  = (const float*)d_in[5];
  const float* U2  = (const float*)d_in[6];
  const float* b2  = (const float*)d_in[7];
  // d_in[8] (Wd), d_in[9] (bd) dead in the reference output.
  float* out = (float*)d_out;

  f16* p1t = (f16*)((char*)d_ws + OFF_P1);
  f16* wf  = (f16*)((char*)d_ws + OFF_WF);
  k_p1<<<10000 / 16, 256, 0, stream>>>(emb, W1, b1, p1t);
  k_split_w16<<<(KT_ALL * 16 * 64 + 255) / 256, 256, 0, stream>>>(W1, U1, W2, U2, wf);
  rnn_ws7<<<BATCH / 16, 512, 0, stream>>>(idx, p1t, wf, b2, out);
}

// Round 5
// 331.095 us; speedup vs baseline: 1.1830x; 1.0170x over previous
//
#include <hip/hip_runtime.h>

// Problem: VOCAB=10000, EMB=100, T=80, UNITS=256, BATCH=4096 — ALL FP32 I/O.
// out = sigmoid(h2_T);  h_l,t = tanh(x_l,t @ Wl + h_l,t-1 @ Ul + bl)
//
// v12 theory (from v11 counters): "+a" pin of 192 regs spilled again (WRITE
// 15MB, VALUBusy 53% of copy/spill code). Budget law from v8..v11: at
// 2 waves/SIMD exactly ~160 pinned regs are spill-free ("+v"), 192 never is.
// v12 keeps v11's cross-t pipeline (1 barrier/iter, shared h1 A-frags) and:
//  - pins U1+W2 (128) + U2-tile-a (32) = 160 regs, "+v" (v8-proven form);
//  - streams only U2-tile-b from LDS (64 KB, imm-offset reads);
//  - P1 via direct global scalar gather -> regs, prefetched one full iter
//    ahead (issued right after acc-init; ~2000cy of MFMA hides L2 latency);
//    the p1s LDS buffer is GONE (its reads/writes/conflicts off the LDS pipe).
// Per-CU-step LDS pipe: 24 b128/wave (vs v8 40) + 16 scalar stores
// ~= 3050 cy; MFMA floor ~1860 cy; 1 barrier. Tripwire: WRITE must stay 4MB.
#define BATCH 4096
#define TLEN  80
#define EMBD  100
#define UNITS 256

typedef _Float16 f16;
typedef __attribute__((ext_vector_type(8))) _Float16 h8;   // 8 f16 = 4 VGPR MFMA A/B frag
typedef __attribute__((ext_vector_type(4))) float f32x4;   // MFMA C/D frag

__device__ __forceinline__ float fast_tanh(float x) {
  x = fminf(fmaxf(x, -15.f), 15.f);
  float e = __expf(-2.f * x);
  return (1.f - e) / (1.f + e);
}
__device__ __forceinline__ float fast_sigmoid(float x) {
  x = fminf(fmaxf(x, -30.f), 30.f);
  return 1.f / (1.f + __expf(-x));
}

// ---------------- workspace layout (5.58 MB <= 6.04 MB proven available) ---
// P1 table: 10000 x 256 f16 = 5,120,000 B.  wf frags: 458,752 B.
// B-frag layout (16x16x32, r7-verified): lane holds B[k=quad*8+j][n=lane&15].
// ktg slots: W1 = 0..3 (unused by main kernel), U1 = 4..11, W2 = 12..19,
// U2 = 20..27.  (kept identical to v8..v11 for layout safety)
#define KT_ALL 28
#define OFF_P1 ((size_t)0)
#define P1_BYTES ((size_t)10000 * UNITS * 2)                // 5,120,000
#define OFF_WF  P1_BYTES
#define WF_BYTES ((size_t)KT_ALL * 16 * 64 * 8 * 2)         //   458,752
#define WS_NEED (OFF_WF + WF_BYTES)                          // 5,578,752 B

__device__ __forceinline__ size_t fidx(int ktg, int nt, int lane) {
  return (((size_t)ktg * 16 + nt) * 64 + lane) * 8;
}

// ---------------- precompute: weights -> swizzled fp16 B-frags (r10-verified)
__global__ __launch_bounds__(256) void k_split_w16(
    const float* __restrict__ W1, const float* __restrict__ U1,
    const float* __restrict__ W2, const float* __restrict__ U2,
    f16* __restrict__ wf)
{
  int gid = blockIdx.x * 256 + threadIdx.x;           // one per (ktg,nt,lane)
  if (gid >= KT_ALL * 16 * 64) return;
  int lane = gid & 63, nt = (gid >> 6) & 15, ktg = gid >> 10;
  const float* M; int Kact, ktl;
  if (ktg < 4)       { M = W1; Kact = EMBD;  ktl = ktg;      }
  else if (ktg < 12) { M = U1; Kact = UNITS; ktl = ktg - 4;  }
  else if (ktg < 20) { M = W2; Kact = UNITS; ktl = ktg - 12; }
  else               { M = U2; Kact = UNITS; ktl = ktg - 20; }
  int n = nt * 16 + (lane & 15);
  int kb = ktl * 32 + (lane >> 4) * 8;
  size_t base = fidx(ktg, nt, lane);
#pragma unroll
  for (int j = 0; j < 8; ++j) {
    int k = kb + j;
    wf[base + j] = (f16)((k < Kact) ? M[(size_t)k * UNITS + n] : 0.f);  // RNE
  }
}

// ---------------- precompute: P1[v][n] = b1[n] + emb[v,:] @ W1 (f32 math) --
__global__ __launch_bounds__(256) void k_p1(
    const float* __restrict__ emb, const float* __restrict__ W1,
    const float* __restrict__ b1, f16* __restrict__ p1t)
{
  __shared__ float er[16][EMBD];
  const int v0 = blockIdx.x * 16;
  for (int i = threadIdx.x; i < 16 * EMBD; i += 256) {
    int vv = i / EMBD, kk = i - vv * EMBD;
    er[vv][kk] = emb[(size_t)(v0 + vv) * EMBD + kk];
  }
  __syncthreads();
  const int n = threadIdx.x;
  float acc[16];
  const float bb = b1[n];
#pragma unroll
  for (int vv = 0; vv < 16; ++vv) acc[vv] = bb;
  for (int k = 0; k < EMBD; ++k) {
    float w = W1[(size_t)k * UNITS + n];
#pragma unroll
    for (int vv = 0; vv < 16; ++vv) acc[vv] += er[vv][k] * w;
  }
#pragma unroll
  for (int vv = 0; vv < 16; ++vv)
    p1t[(size_t)(v0 + vv) * UNITS + n] = (f16)acc[vv];
}

#define MFMA16(A, B, C) __builtin_amdgcn_mfma_f32_16x16x32_f16(A, B, C, 0, 0, 0)

// store tanh result into next-step A-frag (single f16; layout r7-verified):
// elem (row=m, col=k): kt=col>>5, lane'=((col>>3)&3)*16+row, j'=col&7
__device__ __forceinline__ void store_frag1(f16* __restrict__ f, int col, int row, float v) {
  int a = (col >> 5) * 512 + (((col >> 3) & 3) * 16 + row) * 8 + (col & 7);
  f[a] = (f16)v;
}

// ---------------------------------------------------------------------------
// Main kernel v12: 512 thr = 8 waves (2/SIMD), wave w owns n-tiles 2w, 2w+1.
// Iter i: h1[i] = tanh(P1[i] + h1[i-1]@U1);  h2[i-1] = tanh(b2 + h1[i-1]@W2
// + h2[i-2]@U2).  One barrier/iter.  Pinned: U1(a,b) W2(a,b) U2(a) = 160 regs.
// U2(b) streamed from 64 KB dynamic LDS. P1 gathered from global into regs.
// ---------------------------------------------------------------------------
__global__ __launch_bounds__(512, 2)
__attribute__((amdgpu_waves_per_eu(2, 2)))
void rnn_ws8(
    const int* __restrict__ idx, const f16* __restrict__ p1t,
    const f16* __restrict__ wf, const float* __restrict__ b2,
    float* __restrict__ out)
{
  __shared__ __align__(16) f16 f1[2][4096];      // [buf][kt*512 + lane*8 + j]
  __shared__ __align__(16) f16 f2[2][4096];
  extern __shared__ f16 u2s[];                   // 64 KB: odd tiles of U2
                                                 // [(w*8+kt)*64+lane]*8

  const int tid  = threadIdx.x;
  const int lane = tid & 63;
  const int w    = tid >> 6;          // wave 0..7 -> n-tiles 2w, 2w+1
  const int m    = lane & 15;
  const int q    = lane >> 4;
  const int b0   = blockIdx.x * 16;
  const int c0   = (2 * w) * 16 + m;
  const int c1   = (2 * w + 1) * 16 + m;

  const float b2a = b2[c0], b2b = b2[c1];

  // -------- stage U2 odd tiles into LDS (64 KB / 512 thr = 8 h8 each) -----
  for (int d = tid; d < 4096; d += 512) {        // d = (no*8+kt)*64 + l
    int l = d & 63, g = d >> 6, no = g >> 3, kt = g & 7;
    *(h8*)&u2s[(size_t)d * 8] = *(const h8*)(wf + fidx(20 + kt, 2 * no + 1, l));
  }

  // -------- persistent weight fragments: U1(a,b), W2(a,b), U2(a) -----------
  h8 Bu1a[8], Bu1b[8], Bw2a[8], Bw2b[8], Bu2a[8];
#pragma unroll
  for (int kt = 0; kt < 8; ++kt) {
    Bu1a[kt] = *(const h8*)(wf + fidx(4 + kt, 2 * w, lane));
    Bu1b[kt] = *(const h8*)(wf + fidx(4 + kt, 2 * w + 1, lane));
    Bw2a[kt] = *(const h8*)(wf + fidx(12 + kt, 2 * w, lane));
    Bw2b[kt] = *(const h8*)(wf + fidx(12 + kt, 2 * w + 1, lane));
    Bu2a[kt] = *(const h8*)(wf + fidx(20 + kt, 2 * w, lane));
  }
  // pin ("+v", v8-proven at exactly this 160-reg footprint): no remat
#pragma unroll
  for (int kt = 0; kt < 8; ++kt) {
    asm volatile("" : "+v"(Bu1a[kt])); asm volatile("" : "+v"(Bu1b[kt]));
    asm volatile("" : "+v"(Bw2a[kt])); asm volatile("" : "+v"(Bw2b[kt]));
    asm volatile("" : "+v"(Bu2a[kt]));
  }

  // -------- zero h2[-1] state (f2[0]); f1[0] is fully written by the peel --
  for (int i = tid; i < 4096; i += 512) f2[0][i] = (f16)0.f;

  // -------- peel i=0: h1[0] = tanh(P1[0])  (P1 gathered straight to regs) --
  {
#pragma unroll
    for (int r = 0; r < 4; ++r) {
      int row = q * 4 + r;
      int tk = idx[(size_t)(b0 + row) * TLEN + 0];
      const f16* pr = p1t + (size_t)tk * UNITS;
      store_frag1(f1[0], c0, row, fast_tanh((float)pr[c0]));
      store_frag1(f1[0], c1, row, fast_tanh((float)pr[c1]));
    }
  }

  // -------- prefetch P1[1] into regs ---------------------------------------
  float pa[4], pb[4];
#pragma unroll
  for (int r = 0; r < 4; ++r) {
    int tk = idx[(size_t)(b0 + q * 4 + r) * TLEN + 1];
    const f16* pr = p1t + (size_t)tk * UNITS;
    pa[r] = (float)pr[c0];
    pb[r] = (float)pr[c1];
  }
  __syncthreads();   // covers: u2s staging, f2[0] zero, peel writes to f1[0]

  // -------- main loop: i = 1..79 — compute h1[i] and h2[i-1] ---------------
  for (int i = 1; i < TLEN; ++i) {
    const int wr = i & 1, rd = wr ^ 1;

    // acc init: x = P1[i] (b1 folded in, prefetched), yA = b2, yB = 0
    f32x4 x0, x1;
#pragma unroll
    for (int r = 0; r < 4; ++r) { x0[r] = pa[r]; x1[r] = pb[r]; }
    f32x4 yA0 = (f32x4){b2a, b2a, b2a, b2a};
    f32x4 yA1 = (f32x4){b2b, b2b, b2b, b2b};
    f32x4 yB0 = (f32x4){0.f, 0.f, 0.f, 0.f};
    f32x4 yB1 = (f32x4){0.f, 0.f, 0.f, 0.f};

    // prefetch P1[i+1] NOW (overwrites pa/pb after consumption above);
    // ~2000 cy of MFMA below hides the L2 latency.
    if (i + 1 < TLEN) {
#pragma unroll
      for (int r = 0; r < 4; ++r) {
        int tk = idx[(size_t)(b0 + q * 4 + r) * TLEN + (i + 1)];
        const f16* pr = p1t + (size_t)tk * UNITS;
        pa[r] = (float)pr[c0];
        pb[r] = (float)pr[c1];
      }
    }

    // 6 chains x 8 MFMA; a1 (= h1[i-1] frag) feeds both U1 and W2 chains
#pragma unroll
    for (int kt = 0; kt < 8; ++kt) {
      h8 a1 = *(const h8*)&f1[rd][kt * 512 + lane * 8];
      h8 a2 = *(const h8*)&f2[rd][kt * 512 + lane * 8];
      h8 ub = *(const h8*)&u2s[((w * 8 + kt) * 64 + lane) * 8];
      x0  = MFMA16(a1, Bu1a[kt], x0);
      x1  = MFMA16(a1, Bu1b[kt], x1);
      yA0 = MFMA16(a1, Bw2a[kt], yA0);
      yA1 = MFMA16(a1, Bw2b[kt], yA1);
      yB0 = MFMA16(a2, Bu2a[kt], yB0);
      yB1 = MFMA16(a2, ub,       yB1);
    }

    // epilogues: h1[i] -> f1[wr];  h2[i-1] -> f2[wr]
#pragma unroll
    for (int r = 0; r < 4; ++r) {
      int row = q * 4 + r;
      store_frag1(f1[wr], c0, row, fast_tanh(x0[r]));
      store_frag1(f1[wr], c1, row, fast_tanh(x1[r]));
      store_frag1(f2[wr], c0, row, fast_tanh(yA0[r] + yB0[r]));
      store_frag1(f2[wr], c1, row, fast_tanh(yA1[r] + yB1[r]));
    }
    __syncthreads();                 // the ONLY barrier per iteration
  }

  // -------- tail: h2[79] = tanh(b2 + h1[79]@W2 + h2[78]@U2) -> out ---------
  {
    const int rd = (TLEN - 1) & 1;   // = 1: h1[79] in f1[1], h2[78] in f2[1]
    f32x4 yA0 = (f32x4){b2a, b2a, b2a, b2a};
    f32x4 yA1 = (f32x4){b2b, b2b, b2b, b2b};
    f32x4 yB0 = (f32x4){0.f, 0.f, 0.f, 0.f};
    f32x4 yB1 = (f32x4){0.f, 0.f, 0.f, 0.f};
#pragma unroll
    for (int kt = 0; kt < 8; ++kt) {
      h8 a1 = *(const h8*)&f1[rd][kt * 512 + lane * 8];
      h8 a2 = *(const h8*)&f2[rd][kt * 512 + lane * 8];
      h8 ub = *(const h8*)&u2s[((w * 8 + kt) * 64 + lane) * 8];
      yA0 = MFMA16(a1, Bw2a[kt], yA0);
      yA1 = MFMA16(a1, Bw2b[kt], yA1);
      yB0 = MFMA16(a2, Bu2a[kt], yB0);
      yB1 = MFMA16(a2, ub,       yB1);
    }
#pragma unroll
    for (int r = 0; r < 4; ++r) {
      int row = q * 4 + r;
      out[(size_t)(b0 + row) * UNITS + c0] = fast_sigmoid(fast_tanh(yA0[r] + yB0[r]));
      out[(size_t)(b0 + row) * UNITS + c1] = fast_sigmoid(fast_tanh(yA1[r] + yB1[r]));
    }
  }
}

// ---------------------------------------------------------------------------
extern "C" void kernel_launch(void* const* d_in, const int* in_sizes, int n_in,
                              void* d_out, int out_size, void* d_ws, size_t ws_size,
                              hipStream_t stream)
{
  const int*   idx = (const int*)d_in[0];
  const float* emb = (const float*)d_in[1];
  const float* W1  = (const float*)d_in[2];
  const float* U1  = (const float*)d_in[3];
  const float* b1  = (const float*)d_in[4];
  const float* W2  = (const float*)d_in[5];
  const float* U2  = (const float*)d_in[6];
  const float* b2  = (const float*)d_in[7];
  // d_in[8] (Wd), d_in[9] (bd) dead in the reference output.
  float* out = (float*)d_out;

  // 64 KB dynamic + 32 KB static = 96 KB LDS/workgroup -> 1 block/CU.
  static bool attr_done = false;
  if (!attr_done) {
    (void)hipFuncSetAttribute((const void*)rnn_ws8,
                              hipFuncAttributeMaxDynamicSharedMemorySize,
                              65536);
    attr_done = true;
  }

  f16* p1t = (f16*)((char*)d_ws + OFF_P1);
  f16* wf  = (f16*)((char*)d_ws + OFF_WF);
  k_p1<<<10000 / 16, 256, 0, stream>>>(emb, W1, b1, p1t);
  k_split_w16<<<(KT_ALL * 16 * 64 + 255) / 256, 256, 0, stream>>>(W1, U1, W2, U2, wf);
  rnn_ws8<<<BATCH / 16, 512, 65536, stream>>>(idx, p1t, wf, b2, out);
}

// Round 6
// 269.609 us; speedup vs baseline: 1.4527x; 1.2281x over previous
//
#include <hip/hip_runtime.h>

// Problem: VOCAB=10000, EMB=100, T=80, UNITS=256, BATCH=4096 — ALL FP32 I/O.
// out = sigmoid(h2_T);  h_l,t = tanh(x_l,t @ Wl + h_l,t-1 @ Ul + bl)
//
// v13 theory (from v12 counters): iter time stuck ~3.2us across v8/v12
// despite big throughput cuts => serialization at the barrier, not pipes.
// __syncthreads drains vmcnt(0) every iter -> the 2-level P1 gather
// (idx -> p1t, ~600cy) is re-exposed 80 times, slowest-wave-gated. Fixes:
//  - raw "s_waitcnt lgkmcnt(0); s_barrier" (no vmcnt drain): global loads
//    stay in flight across barriers; LDS visibility only needs lgkmcnt.
//  - P1 staged with ONE b128 global load/thread into double-buffered LDS
//    (v11 scheme, at v12's proven 160-reg budget), consumed via cheap LDS
//    b16 reads at acc-init. Kills 12 scalar loads + 64b addr arith/lane.
//  - token loads pipelined one iter ahead of their p1t fetch (de-chained).
// Structure otherwise = v12: 1 barrier/iter, pinned U1+W2+U2a (160 regs),
// U2b from 64KB dynamic LDS, cross-t pipeline (h1[i] & h2[i-1] per iter).
// Tripwire: WRITE_SIZE must stay 4.1 MB.
#define BATCH 4096
#define TLEN  80
#define EMBD  100
#define UNITS 256

typedef _Float16 f16;
typedef __attribute__((ext_vector_type(8))) _Float16 h8;   // 8 f16 = 4 VGPR MFMA A/B frag
typedef __attribute__((ext_vector_type(4))) float f32x4;   // MFMA C/D frag

__device__ __forceinline__ float fast_tanh(float x) {
  x = fminf(fmaxf(x, -15.f), 15.f);
  float e = __expf(-2.f * x);
  return (1.f - e) / (1.f + e);
}
__device__ __forceinline__ float fast_sigmoid(float x) {
  x = fminf(fmaxf(x, -30.f), 30.f);
  return 1.f / (1.f + __expf(-x));
}

// LDS-only barrier: all prior LDS ops visible, but vmcnt NOT drained —
// in-flight global loads (register/LDS-destined) cross the barrier.
__device__ __forceinline__ void block_sync_lds() {
  asm volatile("s_waitcnt lgkmcnt(0)\n\ts_barrier" ::: "memory");
}

// ---------------- workspace layout (5.58 MB <= 6.04 MB proven available) ---
// P1 table: 10000 x 256 f16 = 5,120,000 B.  wf frags: 458,752 B.
// B-frag layout (16x16x32, r7-verified): lane holds B[k=quad*8+j][n=lane&15].
// ktg slots: W1 = 0..3 (unused by main), U1 = 4..11, W2 = 12..19, U2 = 20..27.
#define KT_ALL 28
#define OFF_P1 ((size_t)0)
#define P1_BYTES ((size_t)10000 * UNITS * 2)                // 5,120,000
#define OFF_WF  P1_BYTES
#define WF_BYTES ((size_t)KT_ALL * 16 * 64 * 8 * 2)         //   458,752
#define WS_NEED (OFF_WF + WF_BYTES)                          // 5,578,752 B

__device__ __forceinline__ size_t fidx(int ktg, int nt, int lane) {
  return (((size_t)ktg * 16 + nt) * 64 + lane) * 8;
}

// ---------------- precompute: weights -> swizzled fp16 B-frags (r10-verified)
__global__ __launch_bounds__(256) void k_split_w16(
    const float* __restrict__ W1, const float* __restrict__ U1,
    const float* __restrict__ W2, const float* __restrict__ U2,
    f16* __restrict__ wf)
{
  int gid = blockIdx.x * 256 + threadIdx.x;           // one per (ktg,nt,lane)
  if (gid >= KT_ALL * 16 * 64) return;
  int lane = gid & 63, nt = (gid >> 6) & 15, ktg = gid >> 10;
  const float* M; int Kact, ktl;
  if (ktg < 4)       { M = W1; Kact = EMBD;  ktl = ktg;      }
  else if (ktg < 12) { M = U1; Kact = UNITS; ktl = ktg - 4;  }
  else if (ktg < 20) { M = W2; Kact = UNITS; ktl = ktg - 12; }
  else               { M = U2; Kact = UNITS; ktl = ktg - 20; }
  int n = nt * 16 + (lane & 15);
  int kb = ktl * 32 + (lane >> 4) * 8;
  size_t base = fidx(ktg, nt, lane);
#pragma unroll
  for (int j = 0; j < 8; ++j) {
    int k = kb + j;
    wf[base + j] = (f16)((k < Kact) ? M[(size_t)k * UNITS + n] : 0.f);  // RNE
  }
}

// ---------------- precompute: P1[v][n] = b1[n] + emb[v,:] @ W1 (f32 math) --
__global__ __launch_bounds__(256) void k_p1(
    const float* __restrict__ emb, const float* __restrict__ W1,
    const float* __restrict__ b1, f16* __restrict__ p1t)
{
  __shared__ float er[16][EMBD];
  const int v0 = blockIdx.x * 16;
  for (int i = threadIdx.x; i < 16 * EMBD; i += 256) {
    int vv = i / EMBD, kk = i - vv * EMBD;
    er[vv][kk] = emb[(size_t)(v0 + vv) * EMBD + kk];
  }
  __syncthreads();
  const int n = threadIdx.x;
  float acc[16];
  const float bb = b1[n];
#pragma unroll
  for (int vv = 0; vv < 16; ++vv) acc[vv] = bb;
  for (int k = 0; k < EMBD; ++k) {
    float w = W1[(size_t)k * UNITS + n];
#pragma unroll
    for (int vv = 0; vv < 16; ++vv) acc[vv] += er[vv][k] * w;
  }
#pragma unroll
  for (int vv = 0; vv < 16; ++vv)
    p1t[(size_t)(v0 + vv) * UNITS + n] = (f16)acc[vv];
}

#define MFMA16(A, B, C) __builtin_amdgcn_mfma_f32_16x16x32_f16(A, B, C, 0, 0, 0)

// store tanh result into next-step A-frag (single f16; layout r7-verified):
// elem (row=m, col=k): kt=col>>5, lane'=((col>>3)&3)*16+row, j'=col&7
__device__ __forceinline__ void store_frag1(f16* __restrict__ f, int col, int row, float v) {
  int a = (col >> 5) * 512 + (((col >> 3) & 3) * 16 + row) * 8 + (col & 7);
  f[a] = (f16)v;
}

#define P1S 264   // p1s row stride in f16: 528B = 132 dwords -> rows offset
                  // 4 banks; acc-init reads ~2-way max, writes conflict-free

// ---------------------------------------------------------------------------
// Main kernel v13: 512 thr = 8 waves (2/SIMD), wave w owns n-tiles 2w, 2w+1.
// Iter i: h1[i] = tanh(P1[i] + h1[i-1]@U1);  h2[i-1] = tanh(b2 + h1[i-1]@W2
// + h2[i-2]@U2).  One lgkm-only barrier/iter.
// Pinned: U1(a,b) W2(a,b) U2(a) = 160 regs.  U2(b): 64 KB dynamic LDS.
// P1: 1 b128 global load/thread/iter -> reg -> ds_write -> next-iter LDS read.
// ---------------------------------------------------------------------------
__global__ __launch_bounds__(512, 2)
__attribute__((amdgpu_waves_per_eu(2, 2)))
void rnn_ws9(
    const int* __restrict__ idx, const f16* __restrict__ p1t,
    const f16* __restrict__ wf, const float* __restrict__ b2,
    float* __restrict__ out)
{
  __shared__ __align__(16) f16 f1[2][4096];      // [buf][kt*512 + lane*8 + j]
  __shared__ __align__(16) f16 f2[2][4096];
  __shared__ __align__(16) f16 p1s[2][16 * P1S]; // [buf][row*P1S + col]
  extern __shared__ f16 u2s[];                   // 64 KB: odd tiles of U2

  const int tid  = threadIdx.x;
  const int lane = tid & 63;
  const int w    = tid >> 6;          // wave 0..7 -> n-tiles 2w, 2w+1
  const int m    = lane & 15;
  const int q    = lane >> 4;
  const int b0   = blockIdx.x * 16;
  const int c0   = (2 * w) * 16 + m;
  const int c1   = (2 * w + 1) * 16 + m;

  const float b2a = b2[c0], b2b = b2[c1];

  // P1 staging assignment: thread covers 16B of row srow at offset spart*16B
  const int srow = tid >> 5, spart = tid & 31;
  const int* tokp = idx + (size_t)(b0 + srow) * TLEN;

  // -------- stage U2 odd tiles into LDS (64 KB / 512 thr = 8 h8 each) -----
  for (int d = tid; d < 4096; d += 512) {        // d = (no*8+kt)*64 + l
    int l = d & 63, g = d >> 6, no = g >> 3, kt = g & 7;
    *(h8*)&u2s[(size_t)d * 8] = *(const h8*)(wf + fidx(20 + kt, 2 * no + 1, l));
  }

  // -------- persistent weight fragments: U1(a,b), W2(a,b), U2(a) -----------
  h8 Bu1a[8], Bu1b[8], Bw2a[8], Bw2b[8], Bu2a[8];
#pragma unroll
  for (int kt = 0; kt < 8; ++kt) {
    Bu1a[kt] = *(const h8*)(wf + fidx(4 + kt, 2 * w, lane));
    Bu1b[kt] = *(const h8*)(wf + fidx(4 + kt, 2 * w + 1, lane));
    Bw2a[kt] = *(const h8*)(wf + fidx(12 + kt, 2 * w, lane));
    Bw2b[kt] = *(const h8*)(wf + fidx(12 + kt, 2 * w + 1, lane));
    Bu2a[kt] = *(const h8*)(wf + fidx(20 + kt, 2 * w, lane));
  }
  // pin ("+v", proven spill-free at exactly this 160-reg footprint)
#pragma unroll
  for (int kt = 0; kt < 8; ++kt) {
    asm volatile("" : "+v"(Bu1a[kt])); asm volatile("" : "+v"(Bu1b[kt]));
    asm volatile("" : "+v"(Bw2a[kt])); asm volatile("" : "+v"(Bw2b[kt]));
    asm volatile("" : "+v"(Bu2a[kt]));
  }

  // -------- zero h2[-1] state (f2[0]); f1[0] fully written by the peel -----
  for (int i = tid; i < 4096; i += 512) f2[0][i] = (f16)0.f;

  // -------- peel i=0: h1[0] = tanh(P1[0])  (one-time scalar gather) --------
#pragma unroll
  for (int r = 0; r < 4; ++r) {
    int row = q * 4 + r;
    int tk = idx[(size_t)(b0 + row) * TLEN + 0];
    const f16* pr = p1t + (size_t)tk * UNITS;
    store_frag1(f1[0], c0, row, fast_tanh((float)pr[c0]));
    store_frag1(f1[0], c1, row, fast_tanh((float)pr[c1]));
  }

  // -------- stage P1[1] into p1s[1]; prime token pipeline ------------------
  {
    int tk1 = tokp[1];
    h8 v = *(const h8*)(p1t + (size_t)tk1 * UNITS + spart * 8);
    *(h8*)&p1s[1][srow * P1S + spart * 8] = v;
  }
  int tkn = tokp[2];                   // token for iter1's stage of P1[2]
  __syncthreads();   // full barrier once: u2s, f2 zero, peel, p1s[1]

  // -------- main loop: i = 1..79 — compute h1[i] and h2[i-1] ---------------
  for (int i = 1; i < TLEN; ++i) {
    const int wr = i & 1, rd = wr ^ 1;   // state buffers
    const int pi = i & 1, pn = pi ^ 1;   // p1s buffers

    // (1) issue P1[i+1] row-segment load NOW (consumed by ds_write at iter
    //     end; the whole MFMA section hides L2/L3 latency). Token was loaded
    //     last iter -> no dependent chain on this iter's critical path.
    h8 p1v;
    if (i + 1 < TLEN)
      p1v = *(const h8*)(p1t + (size_t)tkn * UNITS + spart * 8);
    // (2) token for step i+2 (used at iter i+1)
    if (i + 2 < TLEN)
      tkn = tokp[i + 2];

    // (3) acc init: x = P1[i] from LDS (b1 folded in), yA = b2, yB = 0
    f32x4 x0, x1;
#pragma unroll
    for (int r = 0; r < 4; ++r) {
      int row = q * 4 + r;
      x0[r] = (float)p1s[pi][row * P1S + c0];
      x1[r] = (float)p1s[pi][row * P1S + c1];
    }
    f32x4 yA0 = (f32x4){b2a, b2a, b2a, b2a};
    f32x4 yA1 = (f32x4){b2b, b2b, b2b, b2b};
    f32x4 yB0 = (f32x4){0.f, 0.f, 0.f, 0.f};
    f32x4 yB1 = (f32x4){0.f, 0.f, 0.f, 0.f};

    // (4) 6 chains x 8 MFMA; a1 (= h1[i-1] frag) feeds U1 and W2 chains
#pragma unroll
    for (int kt = 0; kt < 8; ++kt) {
      h8 a1 = *(const h8*)&f1[rd][kt * 512 + lane * 8];
      h8 a2 = *(const h8*)&f2[rd][kt * 512 + lane * 8];
      h8 ub = *(const h8*)&u2s[((w * 8 + kt) * 64 + lane) * 8];
      x0  = MFMA16(a1, Bu1a[kt], x0);
      x1  = MFMA16(a1, Bu1b[kt], x1);
      yA0 = MFMA16(a1, Bw2a[kt], yA0);
      yA1 = MFMA16(a1, Bw2b[kt], yA1);
      yB0 = MFMA16(a2, Bu2a[kt], yB0);
      yB1 = MFMA16(a2, ub,       yB1);
    }

    // (5) epilogues: h1[i] -> f1[wr];  h2[i-1] -> f2[wr]
#pragma unroll
    for (int r = 0; r < 4; ++r) {
      int row = q * 4 + r;
      store_frag1(f1[wr], c0, row, fast_tanh(x0[r]));
      store_frag1(f1[wr], c1, row, fast_tanh(x1[r]));
      store_frag1(f2[wr], c0, row, fast_tanh(yA0[r] + yB0[r]));
      store_frag1(f2[wr], c1, row, fast_tanh(yA1[r] + yB1[r]));
    }

    // (6) write staged P1[i+1] (compiler inserts counted vmcnt for p1v)
    if (i + 1 < TLEN)
      *(h8*)&p1s[pn][srow * P1S + spart * 8] = p1v;

    block_sync_lds();        // lgkmcnt-only barrier: vmcnt NOT drained
  }

  // -------- tail: h2[79] = tanh(b2 + h1[79]@W2 + h2[78]@U2) -> out ---------
  {
    const int rd = (TLEN - 1) & 1;   // = 1: h1[79] in f1[1], h2[78] in f2[1]
    f32x4 yA0 = (f32x4){b2a, b2a, b2a, b2a};
    f32x4 yA1 = (f32x4){b2b, b2b, b2b, b2b};
    f32x4 yB0 = (f32x4){0.f, 0.f, 0.f, 0.f};
    f32x4 yB1 = (f32x4){0.f, 0.f, 0.f, 0.f};
#pragma unroll
    for (int kt = 0; kt < 8; ++kt) {
      h8 a1 = *(const h8*)&f1[rd][kt * 512 + lane * 8];
      h8 a2 = *(const h8*)&f2[rd][kt * 512 + lane * 8];
      h8 ub = *(const h8*)&u2s[((w * 8 + kt) * 64 + lane) * 8];
      yA0 = MFMA16(a1, Bw2a[kt], yA0);
      yA1 = MFMA16(a1, Bw2b[kt], yA1);
      yB0 = MFMA16(a2, Bu2a[kt], yB0);
      yB1 = MFMA16(a2, ub,       yB1);
    }
#pragma unroll
    for (int r = 0; r < 4; ++r) {
      int row = q * 4 + r;
      out[(size_t)(b0 + row) * UNITS + c0] = fast_sigmoid(fast_tanh(yA0[r] + yB0[r]));
      out[(size_t)(b0 + row) * UNITS + c1] = fast_sigmoid(fast_tanh(yA1[r] + yB1[r]));
    }
  }
}

// ---------------------------------------------------------------------------
extern "C" void kernel_launch(void* const* d_in, const int* in_sizes, int n_in,
                              void* d_out, int out_size, void* d_ws, size_t ws_size,
                              hipStream_t stream)
{
  const int*   idx = (const int*)d_in[0];
  const float* emb = (const float*)d_in[1];
  const float* W1  = (const float*)d_in[2];
  const float* U1  = (const float*)d_in[3];
  const float* b1  = (const float*)d_in[4];
  const float* W2  = (const float*)d_in[5];
  const float* U2  = (const float*)d_in[6];
  const float* b2  = (const float*)d_in[7];
  // d_in[8] (Wd), d_in[9] (bd) dead in the reference output.
  float* out = (float*)d_out;

  // 64 KB dynamic + ~48.5 KB static ≈ 114 KB LDS/workgroup -> 1 block/CU.
  static bool attr_done = false;
  if (!attr_done) {
    (void)hipFuncSetAttribute((const void*)rnn_ws9,
                              hipFuncAttributeMaxDynamicSharedMemorySize,
                              65536);
    attr_done = true;
  }

  f16* p1t = (f16*)((char*)d_ws + OFF_P1);
  f16* wf  = (f16*)((char*)d_ws + OFF_WF);
  k_p1<<<10000 / 16, 256, 0, stream>>>(emb, W1, b1, p1t);
  k_split_w16<<<(KT_ALL * 16 * 64 + 255) / 256, 256, 0, stream>>>(W1, U1, W2, U2, wf);
  rnn_ws9<<<BATCH / 16, 512, 65536, stream>>>(idx, p1t, wf, b2, out);
}

// Round 7
// 225.647 us; speedup vs baseline: 1.7358x; 1.1948x over previous
//
#include <hip/hip_runtime.h>

// Problem: VOCAB=10000, EMB=100, T=80, UNITS=256, BATCH=4096 — ALL FP32 I/O.
// out = sigmoid(h2_T);  h_l,t = tanh(x_l,t @ Wl + h_l,t-1 @ Ul + bl)
//
// v14 theory (from v13 counters): VALUBusy 62 + MfmaUtil 28 ~= 90% -> issue-
// bound, not stall-bound. Biggest VALU consumer: 16 fast_tanh/lane/iter,
// each compiling (1-e)/(1+e) to the full IEEE div sequence (~10 instr) plus
// 2 clamps => ~17 VALU ops each. Fix: division-free clamp-free tanh:
//   e = exp(-2|x|) in (0,1]  (never overflows -> no clamps),
//   r = (1-e) * v_rcp(1+e)   (HW reciprocal; f16 rounding dwarfs its error),
//   copysign(r, x)           (one v_bfi).
// 8 ops vs 17 -> cuts ~580 cy/SIMD/iter. Sigmoid likewise (rcp-form,
// saturates correctly at both ends, clamp-free). All structure from v13
// kept byte-identical: 160-reg "+v" pin (U1+W2+U2a), U2b in 64KB dynamic
// LDS, lgkm-only barrier (vmcnt stays in flight), P1 b128 staging pipeline.
// Tripwire: WRITE_SIZE must stay 4.1 MB.
#define BATCH 4096
#define TLEN  80
#define EMBD  100
#define UNITS 256

typedef _Float16 f16;
typedef __attribute__((ext_vector_type(8))) _Float16 h8;   // 8 f16 = 4 VGPR MFMA A/B frag
typedef __attribute__((ext_vector_type(4))) float f32x4;   // MFMA C/D frag

// tanh(x) = sign(x) * (1-e)/(1+e), e = exp(-2|x|) in (0,1].
// No clamps needed (e can't overflow); HW rcp instead of IEEE divide.
__device__ __forceinline__ float fast_tanh(float x) {
  float ax = __builtin_fabsf(x);
  float e  = __expf(-2.f * ax);                 // 1 mul (consts fold) + v_exp
  float r  = (1.f - e) * __builtin_amdgcn_rcpf(1.f + e);
  return __builtin_copysignf(r, x);             // v_bfi
}
// sigmoid(x) = rcp(1 + exp(-x)); x->-inf: rcp(inf)=0, x->+inf: rcp(1)=1.
__device__ __forceinline__ float fast_sigmoid(float x) {
  return __builtin_amdgcn_rcpf(1.f + __expf(-x));
}

// LDS-only barrier: all prior LDS ops visible, but vmcnt NOT drained —
// in-flight global loads (register-destined) cross the barrier.
__device__ __forceinline__ void block_sync_lds() {
  asm volatile("s_waitcnt lgkmcnt(0)\n\ts_barrier" ::: "memory");
}

// ---------------- workspace layout (5.58 MB <= 6.04 MB proven available) ---
// P1 table: 10000 x 256 f16 = 5,120,000 B.  wf frags: 458,752 B.
// B-frag layout (16x16x32, r7-verified): lane holds B[k=quad*8+j][n=lane&15].
// ktg slots: W1 = 0..3 (unused by main), U1 = 4..11, W2 = 12..19, U2 = 20..27.
#define KT_ALL 28
#define OFF_P1 ((size_t)0)
#define P1_BYTES ((size_t)10000 * UNITS * 2)                // 5,120,000
#define OFF_WF  P1_BYTES
#define WF_BYTES ((size_t)KT_ALL * 16 * 64 * 8 * 2)         //   458,752
#define WS_NEED (OFF_WF + WF_BYTES)                          // 5,578,752 B

__device__ __forceinline__ size_t fidx(int ktg, int nt, int lane) {
  return (((size_t)ktg * 16 + nt) * 64 + lane) * 8;
}

// ---------------- precompute: weights -> swizzled fp16 B-frags (r10-verified)
__global__ __launch_bounds__(256) void k_split_w16(
    const float* __restrict__ W1, const float* __restrict__ U1,
    const float* __restrict__ W2, const float* __restrict__ U2,
    f16* __restrict__ wf)
{
  int gid = blockIdx.x * 256 + threadIdx.x;           // one per (ktg,nt,lane)
  if (gid >= KT_ALL * 16 * 64) return;
  int lane = gid & 63, nt = (gid >> 6) & 15, ktg = gid >> 10;
  const float* M; int Kact, ktl;
  if (ktg < 4)       { M = W1; Kact = EMBD;  ktl = ktg;      }
  else if (ktg < 12) { M = U1; Kact = UNITS; ktl = ktg - 4;  }
  else if (ktg < 20) { M = W2; Kact = UNITS; ktl = ktg - 12; }
  else               { M = U2; Kact = UNITS; ktl = ktg - 20; }
  int n = nt * 16 + (lane & 15);
  int kb = ktl * 32 + (lane >> 4) * 8;
  size_t base = fidx(ktg, nt, lane);
#pragma unroll
  for (int j = 0; j < 8; ++j) {
    int k = kb + j;
    wf[base + j] = (f16)((k < Kact) ? M[(size_t)k * UNITS + n] : 0.f);  // RNE
  }
}

// ---------------- precompute: P1[v][n] = b1[n] + emb[v,:] @ W1 (f32 math) --
__global__ __launch_bounds__(256) void k_p1(
    const float* __restrict__ emb, const float* __restrict__ W1,
    const float* __restrict__ b1, f16* __restrict__ p1t)
{
  __shared__ float er[16][EMBD];
  const int v0 = blockIdx.x * 16;
  for (int i = threadIdx.x; i < 16 * EMBD; i += 256) {
    int vv = i / EMBD, kk = i - vv * EMBD;
    er[vv][kk] = emb[(size_t)(v0 + vv) * EMBD + kk];
  }
  __syncthreads();
  const int n = threadIdx.x;
  float acc[16];
  const float bb = b1[n];
#pragma unroll
  for (int vv = 0; vv < 16; ++vv) acc[vv] = bb;
  for (int k = 0; k < EMBD; ++k) {
    float w = W1[(size_t)k * UNITS + n];
#pragma unroll
    for (int vv = 0; vv < 16; ++vv) acc[vv] += er[vv][k] * w;
  }
#pragma unroll
  for (int vv = 0; vv < 16; ++vv)
    p1t[(size_t)(v0 + vv) * UNITS + n] = (f16)acc[vv];
}

#define MFMA16(A, B, C) __builtin_amdgcn_mfma_f32_16x16x32_f16(A, B, C, 0, 0, 0)

// store tanh result into next-step A-frag (single f16; layout r7-verified):
// elem (row=m, col=k): kt=col>>5, lane'=((col>>3)&3)*16+row, j'=col&7
__device__ __forceinline__ void store_frag1(f16* __restrict__ f, int col, int row, float v) {
  int a = (col >> 5) * 512 + (((col >> 3) & 3) * 16 + row) * 8 + (col & 7);
  f[a] = (f16)v;
}

#define P1S 264   // p1s row stride in f16: 528B = 132 dwords -> rows offset
                  // 4 banks; acc-init reads ~2-way max, writes conflict-free

// ---------------------------------------------------------------------------
// Main kernel v14: 512 thr = 8 waves (2/SIMD), wave w owns n-tiles 2w, 2w+1.
// Iter i: h1[i] = tanh(P1[i] + h1[i-1]@U1);  h2[i-1] = tanh(b2 + h1[i-1]@W2
// + h2[i-2]@U2).  One lgkm-only barrier/iter.
// Pinned: U1(a,b) W2(a,b) U2(a) = 160 regs.  U2(b): 64 KB dynamic LDS.
// P1: 1 b128 global load/thread/iter -> reg -> ds_write -> next-iter LDS read.
// ---------------------------------------------------------------------------
__global__ __launch_bounds__(512, 2)
__attribute__((amdgpu_waves_per_eu(2, 2)))
void rnn_wsA(
    const int* __restrict__ idx, const f16* __restrict__ p1t,
    const f16* __restrict__ wf, const float* __restrict__ b2,
    float* __restrict__ out)
{
  __shared__ __align__(16) f16 f1[2][4096];      // [buf][kt*512 + lane*8 + j]
  __shared__ __align__(16) f16 f2[2][4096];
  __shared__ __align__(16) f16 p1s[2][16 * P1S]; // [buf][row*P1S + col]
  extern __shared__ f16 u2s[];                   // 64 KB: odd tiles of U2

  const int tid  = threadIdx.x;
  const int lane = tid & 63;
  const int w    = tid >> 6;          // wave 0..7 -> n-tiles 2w, 2w+1
  const int m    = lane & 15;
  const int q    = lane >> 4;
  const int b0   = blockIdx.x * 16;
  const int c0   = (2 * w) * 16 + m;
  const int c1   = (2 * w + 1) * 16 + m;

  const float b2a = b2[c0], b2b = b2[c1];

  // P1 staging assignment: thread covers 16B of row srow at offset spart*16B
  const int srow = tid >> 5, spart = tid & 31;
  const int* tokp = idx + (size_t)(b0 + srow) * TLEN;

  // -------- stage U2 odd tiles into LDS (64 KB / 512 thr = 8 h8 each) -----
  for (int d = tid; d < 4096; d += 512) {        // d = (no*8+kt)*64 + l
    int l = d & 63, g = d >> 6, no = g >> 3, kt = g & 7;
    *(h8*)&u2s[(size_t)d * 8] = *(const h8*)(wf + fidx(20 + kt, 2 * no + 1, l));
  }

  // -------- persistent weight fragments: U1(a,b), W2(a,b), U2(a) -----------
  h8 Bu1a[8], Bu1b[8], Bw2a[8], Bw2b[8], Bu2a[8];
#pragma unroll
  for (int kt = 0; kt < 8; ++kt) {
    Bu1a[kt] = *(const h8*)(wf + fidx(4 + kt, 2 * w, lane));
    Bu1b[kt] = *(const h8*)(wf + fidx(4 + kt, 2 * w + 1, lane));
    Bw2a[kt] = *(const h8*)(wf + fidx(12 + kt, 2 * w, lane));
    Bw2b[kt] = *(const h8*)(wf + fidx(12 + kt, 2 * w + 1, lane));
    Bu2a[kt] = *(const h8*)(wf + fidx(20 + kt, 2 * w, lane));
  }
  // pin ("+v", proven spill-free at exactly this 160-reg footprint)
#pragma unroll
  for (int kt = 0; kt < 8; ++kt) {
    asm volatile("" : "+v"(Bu1a[kt])); asm volatile("" : "+v"(Bu1b[kt]));
    asm volatile("" : "+v"(Bw2a[kt])); asm volatile("" : "+v"(Bw2b[kt]));
    asm volatile("" : "+v"(Bu2a[kt]));
  }

  // -------- zero h2[-1] state (f2[0]); f1[0] fully written by the peel -----
  for (int i = tid; i < 4096; i += 512) f2[0][i] = (f16)0.f;

  // -------- peel i=0: h1[0] = tanh(P1[0])  (one-time scalar gather) --------
#pragma unroll
  for (int r = 0; r < 4; ++r) {
    int row = q * 4 + r;
    int tk = idx[(size_t)(b0 + row) * TLEN + 0];
    const f16* pr = p1t + (size_t)tk * UNITS;
    store_frag1(f1[0], c0, row, fast_tanh((float)pr[c0]));
    store_frag1(f1[0], c1, row, fast_tanh((float)pr[c1]));
  }

  // -------- stage P1[1] into p1s[1]; prime token pipeline ------------------
  {
    int tk1 = tokp[1];
    h8 v = *(const h8*)(p1t + (size_t)tk1 * UNITS + spart * 8);
    *(h8*)&p1s[1][srow * P1S + spart * 8] = v;
  }
  int tkn = tokp[2];                   // token for iter1's stage of P1[2]
  __syncthreads();   // full barrier once: u2s, f2 zero, peel, p1s[1]

  // -------- main loop: i = 1..79 — compute h1[i] and h2[i-1] ---------------
  for (int i = 1; i < TLEN; ++i) {
    const int wr = i & 1, rd = wr ^ 1;   // state buffers
    const int pi = i & 1, pn = pi ^ 1;   // p1s buffers

    // (1) issue P1[i+1] row-segment load NOW (consumed by ds_write at iter
    //     end; the whole MFMA section hides L2/L3 latency). Token was loaded
    //     last iter -> no dependent chain on this iter's critical path.
    h8 p1v;
    if (i + 1 < TLEN)
      p1v = *(const h8*)(p1t + (size_t)tkn * UNITS + spart * 8);
    // (2) token for step i+2 (used at iter i+1)
    if (i + 2 < TLEN)
      tkn = tokp[i + 2];

    // (3) acc init: x = P1[i] from LDS (b1 folded in), yA = b2, yB = 0
    f32x4 x0, x1;
#pragma unroll
    for (int r = 0; r < 4; ++r) {
      int row = q * 4 + r;
      x0[r] = (float)p1s[pi][row * P1S + c0];
      x1[r] = (float)p1s[pi][row * P1S + c1];
    }
    f32x4 yA0 = (f32x4){b2a, b2a, b2a, b2a};
    f32x4 yA1 = (f32x4){b2b, b2b, b2b, b2b};
    f32x4 yB0 = (f32x4){0.f, 0.f, 0.f, 0.f};
    f32x4 yB1 = (f32x4){0.f, 0.f, 0.f, 0.f};

    // (4) 6 chains x 8 MFMA; a1 (= h1[i-1] frag) feeds U1 and W2 chains
#pragma unroll
    for (int kt = 0; kt < 8; ++kt) {
      h8 a1 = *(const h8*)&f1[rd][kt * 512 + lane * 8];
      h8 a2 = *(const h8*)&f2[rd][kt * 512 + lane * 8];
      h8 ub = *(const h8*)&u2s[((w * 8 + kt) * 64 + lane) * 8];
      x0  = MFMA16(a1, Bu1a[kt], x0);
      x1  = MFMA16(a1, Bu1b[kt], x1);
      yA0 = MFMA16(a1, Bw2a[kt], yA0);
      yA1 = MFMA16(a1, Bw2b[kt], yA1);
      yB0 = MFMA16(a2, Bu2a[kt], yB0);
      yB1 = MFMA16(a2, ub,       yB1);
    }

    // (5) epilogues: h1[i] -> f1[wr];  h2[i-1] -> f2[wr]
#pragma unroll
    for (int r = 0; r < 4; ++r) {
      int row = q * 4 + r;
      store_frag1(f1[wr], c0, row, fast_tanh(x0[r]));
      store_frag1(f1[wr], c1, row, fast_tanh(x1[r]));
      store_frag1(f2[wr], c0, row, fast_tanh(yA0[r] + yB0[r]));
      store_frag1(f2[wr], c1, row, fast_tanh(yA1[r] + yB1[r]));
    }

    // (6) write staged P1[i+1] (compiler inserts counted vmcnt for p1v)
    if (i + 1 < TLEN)
      *(h8*)&p1s[pn][srow * P1S + spart * 8] = p1v;

    block_sync_lds();        // lgkmcnt-only barrier: vmcnt NOT drained
  }

  // -------- tail: h2[79] = tanh(b2 + h1[79]@W2 + h2[78]@U2) -> out ---------
  {
    const int rd = (TLEN - 1) & 1;   // = 1: h1[79] in f1[1], h2[78] in f2[1]
    f32x4 yA0 = (f32x4){b2a, b2a, b2a, b2a};
    f32x4 yA1 = (f32x4){b2b, b2b, b2b, b2b};
    f32x4 yB0 = (f32x4){0.f, 0.f, 0.f, 0.f};
    f32x4 yB1 = (f32x4){0.f, 0.f, 0.f, 0.f};
#pragma unroll
    for (int kt = 0; kt < 8; ++kt) {
      h8 a1 = *(const h8*)&f1[rd][kt * 512 + lane * 8];
      h8 a2 = *(const h8*)&f2[rd][kt * 512 + lane * 8];
      h8 ub = *(const h8*)&u2s[((w * 8 + kt) * 64 + lane) * 8];
      yA0 = MFMA16(a1, Bw2a[kt], yA0);
      yA1 = MFMA16(a1, Bw2b[kt], yA1);
      yB0 = MFMA16(a2, Bu2a[kt], yB0);
      yB1 = MFMA16(a2, ub,       yB1);
    }
#pragma unroll
    for (int r = 0; r < 4; ++r) {
      int row = q * 4 + r;
      out[(size_t)(b0 + row) * UNITS + c0] = fast_sigmoid(fast_tanh(yA0[r] + yB0[r]));
      out[(size_t)(b0 + row) * UNITS + c1] = fast_sigmoid(fast_tanh(yA1[r] + yB1[r]));
    }
  }
}

// ---------------------------------------------------------------------------
extern "C" void kernel_launch(void* const* d_in, const int* in_sizes, int n_in,
                              void* d_out, int out_size, void* d_ws, size_t ws_size,
                              hipStream_t stream)
{
  const int*   idx = (const int*)d_in[0];
  const float* emb = (const float*)d_in[1];
  const float* W1  = (const float*)d_in[2];
  const float* U1  = (const float*)d_in[3];
  const float* b1  = (const float*)d_in[4];
  const float* W2  = (const float*)d_in[5];
  const float* U2  = (const float*)d_in[6];
  const float* b2  = (const float*)d_in[7];
  // d_in[8] (Wd), d_in[9] (bd) dead in the reference output.
  float* out = (float*)d_out;

  // 64 KB dynamic + ~48.5 KB static ≈ 114 KB LDS/workgroup -> 1 block/CU.
  static bool attr_done = false;
  if (!attr_done) {
    (void)hipFuncSetAttribute((const void*)rnn_wsA,
                              hipFuncAttributeMaxDynamicSharedMemorySize,
                              65536);
    attr_done = true;
  }

  f16* p1t = (f16*)((char*)d_ws + OFF_P1);
  f16* wf  = (f16*)((char*)d_ws + OFF_WF);
  k_p1<<<10000 / 16, 256, 0, stream>>>(emb, W1, b1, p1t);
  k_split_w16<<<(KT_ALL * 16 * 64 + 255) / 256, 256, 0, stream>>>(W1, U1, W2, U2, wf);
  rnn_wsA<<<BATCH / 16, 512, 65536, stream>>>(idx, p1t, wf, b2, out);
}

// Round 8
// 222.475 us; speedup vs baseline: 1.7605x; 1.0143x over previous
//
#include <hip/hip_runtime.h>

// Problem: VOCAB=10000, EMB=100, T=80, UNITS=256, BATCH=4096 — ALL FP32 I/O.
// out = sigmoid(h2_T);  h_l,t = tanh(x_l,t @ Wl + h_l,t-1 @ Ul + bl)
//
// v15 theory (from v14 counters): VALUBusy 53 + MfmaUtil 36 ~= 89%, and
// v13->v14 proved VALU-instruction removal converts ~1:1 to time. Remaining
// non-math VALU is address arithmetic caused by RUNTIME buffer indices
// (rd/wr/pi/pn): ~49 LDS ops/lane/iter each pay v_add/v_lshl formation
// (~120-150 VALU/lane/iter). Fix: unroll the t-loop x2 so buffer indices
// are compile-time 0/1 -> every static-LDS access = hoisted base VGPR +
// imm16 offset (all offsets < 50KB). Peel the last iteration -> no in-loop
// conditionals; token index clamped branchlessly. Everything else (160-reg
// "+v" pin, U2b in 64KB dynamic LDS, lgkm-only barrier, P1 b128 staging
// pipeline, rcp-tanh) byte-identical to v14.
// Tripwire: WRITE_SIZE must stay 4.1 MB.
#define BATCH 4096
#define TLEN  80
#define EMBD  100
#define UNITS 256

typedef _Float16 f16;
typedef __attribute__((ext_vector_type(8))) _Float16 h8;   // 8 f16 = 4 VGPR MFMA A/B frag
typedef __attribute__((ext_vector_type(4))) float f32x4;   // MFMA C/D frag

// tanh(x) = sign(x) * (1-e)/(1+e), e = exp(-2|x|) in (0,1].
// No clamps needed (e can't overflow); HW rcp instead of IEEE divide.
__device__ __forceinline__ float fast_tanh(float x) {
  float ax = __builtin_fabsf(x);
  float e  = __expf(-2.f * ax);
  float r  = (1.f - e) * __builtin_amdgcn_rcpf(1.f + e);
  return __builtin_copysignf(r, x);
}
// sigmoid(x) = rcp(1 + exp(-x)); saturates correctly at both ends.
__device__ __forceinline__ float fast_sigmoid(float x) {
  return __builtin_amdgcn_rcpf(1.f + __expf(-x));
}

// LDS-only barrier: all prior LDS ops visible, but vmcnt NOT drained —
// in-flight global loads (register-destined) cross the barrier.
__device__ __forceinline__ void block_sync_lds() {
  asm volatile("s_waitcnt lgkmcnt(0)\n\ts_barrier" ::: "memory");
}

// ---------------- workspace layout (5.58 MB <= 6.04 MB proven available) ---
// P1 table: 10000 x 256 f16 = 5,120,000 B.  wf frags: 458,752 B.
// B-frag layout (16x16x32, r7-verified): lane holds B[k=quad*8+j][n=lane&15].
// ktg slots: W1 = 0..3 (unused by main), U1 = 4..11, W2 = 12..19, U2 = 20..27.
#define KT_ALL 28
#define OFF_P1 ((size_t)0)
#define P1_BYTES ((size_t)10000 * UNITS * 2)                // 5,120,000
#define OFF_WF  P1_BYTES
#define WF_BYTES ((size_t)KT_ALL * 16 * 64 * 8 * 2)         //   458,752
#define WS_NEED (OFF_WF + WF_BYTES)                          // 5,578,752 B

__device__ __forceinline__ size_t fidx(int ktg, int nt, int lane) {
  return (((size_t)ktg * 16 + nt) * 64 + lane) * 8;
}

// ---------------- precompute: weights -> swizzled fp16 B-frags (r10-verified)
__global__ __launch_bounds__(256) void k_split_w16(
    const float* __restrict__ W1, const float* __restrict__ U1,
    const float* __restrict__ W2, const float* __restrict__ U2,
    f16* __restrict__ wf)
{
  int gid = blockIdx.x * 256 + threadIdx.x;           // one per (ktg,nt,lane)
  if (gid >= KT_ALL * 16 * 64) return;
  int lane = gid & 63, nt = (gid >> 6) & 15, ktg = gid >> 10;
  const float* M; int Kact, ktl;
  if (ktg < 4)       { M = W1; Kact = EMBD;  ktl = ktg;      }
  else if (ktg < 12) { M = U1; Kact = UNITS; ktl = ktg - 4;  }
  else if (ktg < 20) { M = W2; Kact = UNITS; ktl = ktg - 12; }
  else               { M = U2; Kact = UNITS; ktl = ktg - 20; }
  int n = nt * 16 + (lane & 15);
  int kb = ktl * 32 + (lane >> 4) * 8;
  size_t base = fidx(ktg, nt, lane);
#pragma unroll
  for (int j = 0; j < 8; ++j) {
    int k = kb + j;
    wf[base + j] = (f16)((k < Kact) ? M[(size_t)k * UNITS + n] : 0.f);  // RNE
  }
}

// ---------------- precompute: P1[v][n] = b1[n] + emb[v,:] @ W1 (f32 math) --
__global__ __launch_bounds__(256) void k_p1(
    const float* __restrict__ emb, const float* __restrict__ W1,
    const float* __restrict__ b1, f16* __restrict__ p1t)
{
  __shared__ float er[16][EMBD];
  const int v0 = blockIdx.x * 16;
  for (int i = threadIdx.x; i < 16 * EMBD; i += 256) {
    int vv = i / EMBD, kk = i - vv * EMBD;
    er[vv][kk] = emb[(size_t)(v0 + vv) * EMBD + kk];
  }
  __syncthreads();
  const int n = threadIdx.x;
  float acc[16];
  const float bb = b1[n];
#pragma unroll
  for (int vv = 0; vv < 16; ++vv) acc[vv] = bb;
  for (int k = 0; k < EMBD; ++k) {
    float w = W1[(size_t)k * UNITS + n];
#pragma unroll
    for (int vv = 0; vv < 16; ++vv) acc[vv] += er[vv][k] * w;
  }
#pragma unroll
  for (int vv = 0; vv < 16; ++vv)
    p1t[(size_t)(v0 + vv) * UNITS + n] = (f16)acc[vv];
}

#define MFMA16(A, B, C) __builtin_amdgcn_mfma_f32_16x16x32_f16(A, B, C, 0, 0, 0)

// store tanh result into next-step A-frag (single f16; layout r7-verified):
// elem (row=m, col=k): kt=col>>5, lane'=((col>>3)&3)*16+row, j'=col&7
__device__ __forceinline__ void store_frag1(f16* __restrict__ f, int col, int row, float v) {
  int a = (col >> 5) * 512 + (((col >> 3) & 3) * 16 + row) * 8 + (col & 7);
  f[a] = (f16)v;
}

#define P1S 264   // p1s row stride in f16: 528B = 132 dwords -> rows offset
                  // 4 banks; acc-init reads ~2-way max, writes conflict-free

// ---------------------------------------------------------------------------
// Main kernel v15: 512 thr = 8 waves (2/SIMD), wave w owns n-tiles 2w, 2w+1.
// Iter i: h1[i] = tanh(P1[i] + h1[i-1]@U1);  h2[i-1] = tanh(b2 + h1[i-1]@W2
// + h2[i-2]@U2).  One lgkm-only barrier/iter.  t-loop unrolled x2 so all
// LDS buffer indices are compile-time -> imm16 offsets, no addr VALU.
// Pinned: U1(a,b) W2(a,b) U2(a) = 160 regs.  U2(b): 64 KB dynamic LDS.
// ---------------------------------------------------------------------------
__global__ __launch_bounds__(512, 2)
__attribute__((amdgpu_waves_per_eu(2, 2)))
void rnn_wsB(
    const int* __restrict__ idx, const f16* __restrict__ p1t,
    const f16* __restrict__ wf, const float* __restrict__ b2,
    float* __restrict__ out)
{
  __shared__ __align__(16) f16 f1[2][4096];      // [buf][kt*512 + lane*8 + j]
  __shared__ __align__(16) f16 f2[2][4096];
  __shared__ __align__(16) f16 p1s[2][16 * P1S]; // [buf][row*P1S + col]
  extern __shared__ f16 u2s[];                   // 64 KB: odd tiles of U2

  const int tid  = threadIdx.x;
  const int lane = tid & 63;
  const int w    = tid >> 6;          // wave 0..7 -> n-tiles 2w, 2w+1
  const int m    = lane & 15;
  const int q    = lane >> 4;
  const int b0   = blockIdx.x * 16;
  const int c0   = (2 * w) * 16 + m;
  const int c1   = (2 * w + 1) * 16 + m;

  const float b2a = b2[c0], b2b = b2[c1];

  // P1 staging assignment: thread covers 16B of row srow at offset spart*16B
  const int srow = tid >> 5, spart = tid & 31;
  const int* tokp = idx + (size_t)(b0 + srow) * TLEN;
  const f16* p1g  = p1t + spart * 8;             // hoisted gather base

  // -------- stage U2 odd tiles into LDS (64 KB / 512 thr = 8 h8 each) -----
  for (int d = tid; d < 4096; d += 512) {        // d = (no*8+kt)*64 + l
    int l = d & 63, g = d >> 6, no = g >> 3, kt = g & 7;
    *(h8*)&u2s[(size_t)d * 8] = *(const h8*)(wf + fidx(20 + kt, 2 * no + 1, l));
  }

  // -------- persistent weight fragments: U1(a,b), W2(a,b), U2(a) -----------
  h8 Bu1a[8], Bu1b[8], Bw2a[8], Bw2b[8], Bu2a[8];
#pragma unroll
  for (int kt = 0; kt < 8; ++kt) {
    Bu1a[kt] = *(const h8*)(wf + fidx(4 + kt, 2 * w, lane));
    Bu1b[kt] = *(const h8*)(wf + fidx(4 + kt, 2 * w + 1, lane));
    Bw2a[kt] = *(const h8*)(wf + fidx(12 + kt, 2 * w, lane));
    Bw2b[kt] = *(const h8*)(wf + fidx(12 + kt, 2 * w + 1, lane));
    Bu2a[kt] = *(const h8*)(wf + fidx(20 + kt, 2 * w, lane));
  }
  // pin ("+v", proven spill-free at exactly this 160-reg footprint)
#pragma unroll
  for (int kt = 0; kt < 8; ++kt) {
    asm volatile("" : "+v"(Bu1a[kt])); asm volatile("" : "+v"(Bu1b[kt]));
    asm volatile("" : "+v"(Bw2a[kt])); asm volatile("" : "+v"(Bw2b[kt]));
    asm volatile("" : "+v"(Bu2a[kt]));
  }

  // -------- zero h2[-1] state (f2[0]); f1[0] fully written by the peel -----
  for (int i = tid; i < 4096; i += 512) f2[0][i] = (f16)0.f;

  // -------- peel i=0: h1[0] = tanh(P1[0])  (one-time scalar gather) --------
#pragma unroll
  for (int r = 0; r < 4; ++r) {
    int row = q * 4 + r;
    int tk = idx[(size_t)(b0 + row) * TLEN + 0];
    const f16* pr = p1t + (size_t)tk * UNITS;
    store_frag1(f1[0], c0, row, fast_tanh((float)pr[c0]));
    store_frag1(f1[0], c1, row, fast_tanh((float)pr[c1]));
  }

  // -------- stage P1[1] into p1s[1]; prime token pipeline ------------------
  {
    int tk1 = tokp[1];
    h8 v = *(const h8*)(p1g + (size_t)tk1 * UNITS);
    *(h8*)&p1s[1][srow * P1S + spart * 8] = v;
  }
  int tkn = tokp[2];                   // token for iter1's stage of P1[2]
  __syncthreads();   // full barrier once: u2s, f2 zero, peel, p1s[1]

  // ======== one pipelined step; RD/WR are COMPILE-TIME 0/1 =================
  // STAGE: 1 = stage P1 for step (this+1) into p1s[RD]; TKI = token index to
  // prefetch (clamped by caller). Reads f1[RD],f2[RD],p1s[WR]; writes
  // f1[WR],f2[WR],p1s[RD].
#define RNN_STEP(RD, WR, STAGE, TKI)                                         \
  {                                                                          \
    h8 p1v;                                                                  \
    if (STAGE) p1v = *(const h8*)(p1g + (size_t)tkn * UNITS);                \
    tkn = tokp[TKI];                                                         \
    f32x4 x0, x1;                                                            \
    _Pragma("unroll")                                                        \
    for (int r = 0; r < 4; ++r) {                                            \
      int row = q * 4 + r;                                                   \
      x0[r] = (float)p1s[WR][row * P1S + c0];                                \
      x1[r] = (float)p1s[WR][row * P1S + c1];                                \
    }                                                                        \
    f32x4 yA0 = (f32x4){b2a, b2a, b2a, b2a};                                 \
    f32x4 yA1 = (f32x4){b2b, b2b, b2b, b2b};                                 \
    f32x4 yB0 = (f32x4){0.f, 0.f, 0.f, 0.f};                                 \
    f32x4 yB1 = (f32x4){0.f, 0.f, 0.f, 0.f};                                 \
    _Pragma("unroll")                                                        \
    for (int kt = 0; kt < 8; ++kt) {                                         \
      h8 a1 = *(const h8*)&f1[RD][kt * 512 + lane * 8];                      \
      h8 a2 = *(const h8*)&f2[RD][kt * 512 + lane * 8];                      \
      h8 ub = *(const h8*)&u2s[((w * 8 + kt) * 64 + lane) * 8];              \
      x0  = MFMA16(a1, Bu1a[kt], x0);                                        \
      x1  = MFMA16(a1, Bu1b[kt], x1);                                        \
      yA0 = MFMA16(a1, Bw2a[kt], yA0);                                       \
      yA1 = MFMA16(a1, Bw2b[kt], yA1);                                       \
      yB0 = MFMA16(a2, Bu2a[kt], yB0);                                       \
      yB1 = MFMA16(a2, ub,       yB1);                                       \
    }                                                                        \
    _Pragma("unroll")                                                        \
    for (int r = 0; r < 4; ++r) {                                            \
      int row = q * 4 + r;                                                   \
      store_frag1(f1[WR], c0, row, fast_tanh(x0[r]));                        \
      store_frag1(f1[WR], c1, row, fast_tanh(x1[r]));                        \
      store_frag1(f2[WR], c0, row, fast_tanh(yA0[r] + yB0[r]));              \
      store_frag1(f2[WR], c1, row, fast_tanh(yA1[r] + yB1[r]));              \
    }                                                                        \
    if (STAGE) *(h8*)&p1s[RD][srow * P1S + spart * 8] = p1v;                 \
    block_sync_lds();                                                        \
  }

  // -------- main loop: 39 pairs cover i = 1..78; i = 79 peeled -------------
  for (int i = 1; i < TLEN - 1; i += 2) {
    int t2 = i + 3 < TLEN - 1 ? i + 3 : TLEN - 1;   // clamp (last pair only)
    RNN_STEP(0, 1, true, i + 2);    // i odd:  reads buf0, writes buf1
    RNN_STEP(1, 0, true, t2);       // i+1:    reads buf1, writes buf0
  }
  RNN_STEP(0, 1, false, TLEN - 1);  // i = 79: no staging (tkn load harmless)
#undef RNN_STEP

  // -------- tail: h2[79] = tanh(b2 + h1[79]@W2 + h2[78]@U2) -> out ---------
  {
    f32x4 yA0 = (f32x4){b2a, b2a, b2a, b2a};
    f32x4 yA1 = (f32x4){b2b, b2b, b2b, b2b};
    f32x4 yB0 = (f32x4){0.f, 0.f, 0.f, 0.f};
    f32x4 yB1 = (f32x4){0.f, 0.f, 0.f, 0.f};
#pragma unroll
    for (int kt = 0; kt < 8; ++kt) {
      h8 a1 = *(const h8*)&f1[1][kt * 512 + lane * 8];   // h1[79]
      h8 a2 = *(const h8*)&f2[1][kt * 512 + lane * 8];   // h2[78]
      h8 ub = *(const h8*)&u2s[((w * 8 + kt) * 64 + lane) * 8];
      yA0 = MFMA16(a1, Bw2a[kt], yA0);
      yA1 = MFMA16(a1, Bw2b[kt], yA1);
      yB0 = MFMA16(a2, Bu2a[kt], yB0);
      yB1 = MFMA16(a2, ub,       yB1);
    }
#pragma unroll
    for (int r = 0; r < 4; ++r) {
      int row = q * 4 + r;
      out[(size_t)(b0 + row) * UNITS + c0] = fast_sigmoid(fast_tanh(yA0[r] + yB0[r]));
      out[(size_t)(b0 + row) * UNITS + c1] = fast_sigmoid(fast_tanh(yA1[r] + yB1[r]));
    }
  }
}

// ---------------------------------------------------------------------------
extern "C" void kernel_launch(void* const* d_in, const int* in_sizes, int n_in,
                              void* d_out, int out_size, void* d_ws, size_t ws_size,
                              hipStream_t stream)
{
  const int*   idx = (const int*)d_in[0];
  const float* emb = (const float*)d_in[1];
  const float* W1  = (const float*)d_in[2];
  const float* U1  = (const float*)d_in[3];
  const float* b1  = (const float*)d_in[4];
  const float* W2  = (const float*)d_in[5];
  const float* U2  = (const float*)d_in[6];
  const float* b2  = (const float*)d_in[7];
  // d_in[8] (Wd), d_in[9] (bd) dead in the reference output.
  float* out = (float*)d_out;

  // 64 KB dynamic + ~48.5 KB static ≈ 114 KB LDS/workgroup -> 1 block/CU.
  static bool attr_done = false;
  if (!attr_done) {
    (void)hipFuncSetAttribute((const void*)rnn_wsB,
                              hipFuncAttributeMaxDynamicSharedMemorySize,
                              65536);
    attr_done = true;
  }

  f16* p1t = (f16*)((char*)d_ws + OFF_P1);
  f16* wf  = (f16*)((char*)d_ws + OFF_WF);
  k_p1<<<10000 / 16, 256, 0, stream>>>(emb, W1, b1, p1t);
  k_split_w16<<<(KT_ALL * 16 * 64 + 255) / 256, 256, 0, stream>>>(W1, U1, W2, U2, wf);
  rnn_wsB<<<BATCH / 16, 512, 65536, stream>>>(idx, p1t, wf, b2, out);
}